// Round 7
// baseline (484.490 us; speedup 1.0000x reference)
//
#include <hip/hip_runtime.h>
#include <hip/hip_bf16.h>

#define NEG_SLOPE 0.2f

// ---------------------------------------------------------------------------
// GAT 2-layer, N=100k, E=3.2M (+self-loops handled analytically per node).
//
// R7: sort edges by dst into 64-node buckets (NBK=1563) directly, instead of
// R5/R6's 256-node buckets + 4-window filtering. Aggregation blocks now read
// a private contiguous pair segment with all lanes useful (R6 counters:
// FETCH 57MB = 4x pairs re-read, 1/4 lane efficiency in masked sections ->
// both VMEM and LDS-atomic pipes fed at 1/4 useful rate).
//   - bucket_hist (128x256): LDS hist of 2048 counters, 262K flush atomics
//   - scan_init (1x512):     512 threads x 4 buckets each, Hillis-Steele
//   - bucket_scatter (256x1024): 3-phase, reserve atomic per (block,bucket)
//   - l1_seg/l2_seg (NBKx256): private segment, 64x9 LDS accumulator,
//     zero filtering, per-node epilogues as before
//
// Layer 1 collapses because IN==1 (h1 = x*W1 is rank-1):
//   logit_src[n,h]=x[n]*S1[h], logit_dst[n,h]=x[n]*D1[h],
//   out1[n,h,c]=W1[h,c]*t1[n,h]+b1. No softmax max-subtraction needed
//   (|logit| <~ 30, exp safe in fp32; verified R2-R6 absmax 9.8e-4).
//
// ws layout (4B units):
//   [0..15]        consts S1[4],D1[4]
//   [16..2063]     gcnt[2048]   (zeroed)
//   [2064..4111]   gbase[2048]
//   [4112..6159]   gcursor[2048]
//   [+N]           als2
//   [+N]           ald2
//   [+8N]          h2
//   [+E]           pairs (packed src | local_dst<<17, local 6 bits)
// Guards: N <= 131072 (17-bit src, NBK<=2048). Fallback: R2 atomic path.
// ---------------------------------------------------------------------------

__global__ void prep_consts(const float* __restrict__ W1,
                            const float* __restrict__ as1,
                            const float* __restrict__ ad1,
                            float* __restrict__ consts) {
    int t = threadIdx.x;
    if (t >= 8) return;
    int h = t & 3;
    const float* a = (t < 4) ? as1 : ad1;
    float s = 0.f;
    #pragma unroll
    for (int c = 0; c < 8; ++c)
        s += W1[h * 8 + c] * a[h * 8 + c];
    consts[t] = s;
}

__global__ void bucket_hist(const int* __restrict__ ei, int* __restrict__ gcnt, int E) {
    __shared__ int cnt[2048];
    int t = threadIdx.x;
    for (int i = t; i < 2048; i += 256) cnt[i] = 0;
    __syncthreads();
    int stride = gridDim.x * 256;
    for (int e = blockIdx.x * 256 + t; e < E; e += stride)
        atomicAdd(&cnt[ei[E + e] >> 6], 1);
    __syncthreads();
    for (int i = t; i < 2048; i += 256) {
        int c = cnt[i];
        if (c) atomicAdd(&gcnt[i], c);
    }
}

// single block, 512 threads; each owns 4 consecutive buckets (2048 total).
__global__ void scan_init(const int* __restrict__ gcnt,
                          int* __restrict__ gbase, int* __restrict__ gcursor) {
    __shared__ int buf[512];
    int t = threadIdx.x;
    int c0 = gcnt[t * 4], c1 = gcnt[t * 4 + 1], c2 = gcnt[t * 4 + 2], c3 = gcnt[t * 4 + 3];
    int sum = c0 + c1 + c2 + c3;
    buf[t] = sum;
    __syncthreads();
    for (int o = 1; o < 512; o <<= 1) {
        int add = (t >= o) ? buf[t - o] : 0;
        __syncthreads();
        buf[t] += add;
        __syncthreads();
    }
    int base = buf[t] - sum;                       // exclusive
    gbase[t * 4] = base;     gcursor[t * 4] = base;     base += c0;
    gbase[t * 4 + 1] = base; gcursor[t * 4 + 1] = base; base += c1;
    gbase[t * 4 + 2] = base; gcursor[t * 4 + 2] = base; base += c2;
    gbase[t * 4 + 3] = base; gcursor[t * 4 + 3] = base;
}

__global__ void bucket_scatter(const int* __restrict__ ei, int* __restrict__ gcursor,
                               unsigned int* __restrict__ pairs, int E) {
    __shared__ int cnt[2048];
    __shared__ int basel[2048];
    int t = threadIdx.x;
    int chunk = (E + gridDim.x - 1) / gridDim.x;
    int lo = blockIdx.x * chunk;
    int hi = min(E, lo + chunk);
    for (int i = t; i < 2048; i += 1024) cnt[i] = 0;
    __syncthreads();
    for (int e = lo + t; e < hi; e += 1024)
        atomicAdd(&cnt[ei[E + e] >> 6], 1);
    __syncthreads();
    for (int i = t; i < 2048; i += 1024) {
        int c = cnt[i];
        basel[i] = c ? atomicAdd(&gcursor[i], c) : 0;
        cnt[i] = 0;
    }
    __syncthreads();
    for (int e = lo + t; e < hi; e += 1024) {
        int s = ei[e];
        int d = ei[E + e];
        int bk = d >> 6;
        int loc = atomicAdd(&cnt[bk], 1);
        pairs[basel[bk] + loc] = (unsigned)s | ((unsigned)(d & 63) << 17);
    }
}

// Layer-1 aggregation + epilogue + W2 transform + layer-2 logits.
// One block per 64-node bucket; private contiguous segment, no filtering.
__global__ void l1_seg(const float* __restrict__ x,
                       const int* __restrict__ gbase, const int* __restrict__ gcnt,
                       const unsigned int* __restrict__ pairs,
                       const float* __restrict__ consts,
                       const float* __restrict__ W1, const float* __restrict__ b1,
                       const float* __restrict__ W2,
                       const float* __restrict__ as2, const float* __restrict__ ad2,
                       float* __restrict__ h2, float* __restrict__ als2,
                       float* __restrict__ ald2, int N) {
    __shared__ float st[64 * 9];   // rows: [0..3]=s1[h], [4..7]=t1[h] (stride 9)
    __shared__ float xl[64];
    int t = threadIdx.x;
    int bk = blockIdx.x;
    int node0 = bk << 6;
    int nw = min(64, N - node0);
    if (t < 64) {
        #pragma unroll
        for (int j = 0; j < 9; ++j) st[t * 9 + j] = 0.f;
        if (t < nw) xl[t] = x[node0 + t];
    }
    float S[4], D[4];
    #pragma unroll
    for (int h = 0; h < 4; ++h) { S[h] = consts[h]; D[h] = consts[4 + h]; }
    __syncthreads();
    int b = gbase[bk];
    int hi = b + gcnt[bk];
    for (int i = b + t; i < hi; i += 256) {
        unsigned p = pairs[i];
        int src = (int)(p & 131071u);
        int ld = (int)(p >> 17);
        float xs = x[src];
        float xd = xl[ld];
        float* row = &st[ld * 9];
        #pragma unroll
        for (int h = 0; h < 4; ++h) {
            float v = xs * S[h] + xd * D[h];
            v = (v > 0.f) ? v : NEG_SLOPE * v;
            float ww = __expf(v);
            atomicAdd(&row[h], ww);
            atomicAdd(&row[4 + h], ww * xs);
        }
    }
    __syncthreads();
    if (t < nw) {
        int n = node0 + t;
        float xn = xl[t];
        float o[8];
        #pragma unroll
        for (int c = 0; c < 8; ++c) o[c] = 0.f;
        #pragma unroll
        for (int h = 0; h < 4; ++h) {
            float v = xn * (S[h] + D[h]);           // self-loop term
            v = (v > 0.f) ? v : NEG_SLOPE * v;
            float ww = __expf(v);
            float s1 = st[t * 9 + h] + ww;
            float tt = (st[t * 9 + 4 + h] + ww * xn) / s1;
            #pragma unroll
            for (int c = 0; c < 8; ++c) {
                float r = fmaxf(tt * W1[h * 8 + c] + b1[h * 8 + c], 0.f);
                #pragma unroll
                for (int c2 = 0; c2 < 8; ++c2) o[c2] += r * W2[(h * 8 + c) * 8 + c2];
            }
        }
        float as = 0.f, ad = 0.f;
        #pragma unroll
        for (int c = 0; c < 8; ++c) { as += o[c] * as2[c]; ad += o[c] * ad2[c]; }
        float4* hv = (float4*)&h2[(size_t)n * 8];
        hv[0] = make_float4(o[0], o[1], o[2], o[3]);
        hv[1] = make_float4(o[4], o[5], o[6], o[7]);
        als2[n] = as;
        ald2[n] = ad;
    }
}

// Layer-2 aggregation + output epilogue, one block per 64-node bucket.
__global__ void l2_seg(const int* __restrict__ gbase, const int* __restrict__ gcnt,
                       const unsigned int* __restrict__ pairs,
                       const float* __restrict__ als2, const float* __restrict__ ald2,
                       const float* __restrict__ h2, const float* __restrict__ b2,
                       float* __restrict__ out, int N) {
    __shared__ float sa[64 * 9];   // rows: [0]=s2, [1..8]=acc (stride 9)
    __shared__ float all[64], adl[64];
    int t = threadIdx.x;
    int bk = blockIdx.x;
    int node0 = bk << 6;
    int nw = min(64, N - node0);
    if (t < 64) {
        #pragma unroll
        for (int j = 0; j < 9; ++j) sa[t * 9 + j] = 0.f;
        if (t < nw) { all[t] = als2[node0 + t]; adl[t] = ald2[node0 + t]; }
    }
    __syncthreads();
    int b = gbase[bk];
    int hi = b + gcnt[bk];
    for (int i = b + t; i < hi; i += 256) {
        unsigned p = pairs[i];
        int src = (int)(p & 131071u);
        int ld = (int)(p >> 17);
        float v = als2[src] + adl[ld];
        v = (v > 0.f) ? v : NEG_SLOPE * v;
        float ww = __expf(v);
        const float4* hv = (const float4*)&h2[(size_t)src * 8];
        float4 ha = hv[0], hb = hv[1];
        float* row = &sa[ld * 9];
        atomicAdd(&row[0], ww);
        atomicAdd(&row[1], ww * ha.x); atomicAdd(&row[2], ww * ha.y);
        atomicAdd(&row[3], ww * ha.z); atomicAdd(&row[4], ww * ha.w);
        atomicAdd(&row[5], ww * hb.x); atomicAdd(&row[6], ww * hb.y);
        atomicAdd(&row[7], ww * hb.z); atomicAdd(&row[8], ww * hb.w);
    }
    __syncthreads();
    if (t < nw) {
        int n = node0 + t;
        float v = all[t] + adl[t];               // self-loop
        v = (v > 0.f) ? v : NEG_SLOPE * v;
        float ww = __expf(v);
        const float4* hv = (const float4*)&h2[(size_t)n * 8];
        float4 ha0 = hv[0], hb0 = hv[1];
        float s2 = sa[t * 9] + ww;
        float inv = 1.f / s2;
        float4* ov = (float4*)&out[(size_t)n * 8];
        ov[0] = make_float4((sa[t * 9 + 1] + ww * ha0.x) * inv + b2[0],
                            (sa[t * 9 + 2] + ww * ha0.y) * inv + b2[1],
                            (sa[t * 9 + 3] + ww * ha0.z) * inv + b2[2],
                            (sa[t * 9 + 4] + ww * ha0.w) * inv + b2[3]);
        ov[1] = make_float4((sa[t * 9 + 5] + ww * hb0.x) * inv + b2[4],
                            (sa[t * 9 + 6] + ww * hb0.y) * inv + b2[5],
                            (sa[t * 9 + 7] + ww * hb0.z) * inv + b2[6],
                            (sa[t * 9 + 8] + ww * hb0.w) * inv + b2[7]);
    }
}

// ---------------- fallback path (R2, atomic-based; known-correct) ----------------

__global__ void edge_pass1(const int* __restrict__ ei, const float* __restrict__ x,
                           const float* __restrict__ consts,
                           float* __restrict__ s1, float* __restrict__ t1, int E, int N) {
    int e = blockIdx.x * blockDim.x + threadIdx.x;
    if (e >= E + N) return;
    int src, dst;
    if (e < E) { src = ei[e]; dst = ei[E + e]; }
    else       { src = dst = e - E; }
    float xs = x[src], xd = x[dst];
    #pragma unroll
    for (int h = 0; h < 4; ++h) {
        float v = xs * consts[h] + xd * consts[4 + h];
        v = (v > 0.f) ? v : NEG_SLOPE * v;
        float w = __expf(v);
        atomicAdd(&s1[dst * 4 + h], w);
        atomicAdd(&t1[dst * 4 + h], w * xs);
    }
}

__global__ void node_mid(const float* __restrict__ s1, const float* __restrict__ t1,
                         const float* __restrict__ W1, const float* __restrict__ b1,
                         const float* __restrict__ W2,
                         const float* __restrict__ as2, const float* __restrict__ ad2,
                         float* __restrict__ h2, float* __restrict__ als2,
                         float* __restrict__ ald2, int N) {
    int n = blockIdx.x * blockDim.x + threadIdx.x;
    if (n >= N) return;
    float o[8];
    #pragma unroll
    for (int c = 0; c < 8; ++c) o[c] = 0.f;
    #pragma unroll
    for (int h = 0; h < 4; ++h) {
        float t = t1[n * 4 + h] / s1[n * 4 + h];
        #pragma unroll
        for (int c = 0; c < 8; ++c) {
            float r = fmaxf(t * W1[h * 8 + c] + b1[h * 8 + c], 0.f);
            #pragma unroll
            for (int c2 = 0; c2 < 8; ++c2) o[c2] += r * W2[(h * 8 + c) * 8 + c2];
        }
    }
    float as = 0.f, ad = 0.f;
    #pragma unroll
    for (int c = 0; c < 8; ++c) { h2[n * 8 + c] = o[c]; as += o[c] * as2[c]; ad += o[c] * ad2[c]; }
    als2[n] = as; ald2[n] = ad;
}

__global__ void edge_pass2(const int* __restrict__ ei, const float* __restrict__ als2,
                           const float* __restrict__ ald2, const float* __restrict__ h2,
                           float* __restrict__ s2, float* __restrict__ acc2, int E, int N) {
    int e = blockIdx.x * blockDim.x + threadIdx.x;
    if (e >= E + N) return;
    int src, dst;
    if (e < E) { src = ei[e]; dst = ei[E + e]; }
    else       { src = dst = e - E; }
    float v = als2[src] + ald2[dst];
    v = (v > 0.f) ? v : NEG_SLOPE * v;
    float w = __expf(v);
    atomicAdd(&s2[dst], w);
    const float4* hs = (const float4*)&h2[src * 8];
    float4 a = hs[0], bq = hs[1];
    float* acc = &acc2[dst * 8];
    atomicAdd(&acc[0], w * a.x);  atomicAdd(&acc[1], w * a.y);
    atomicAdd(&acc[2], w * a.z);  atomicAdd(&acc[3], w * a.w);
    atomicAdd(&acc[4], w * bq.x); atomicAdd(&acc[5], w * bq.y);
    atomicAdd(&acc[6], w * bq.z); atomicAdd(&acc[7], w * bq.w);
}

__global__ void node_out(const float* __restrict__ s2, const float* __restrict__ acc2,
                         const float* __restrict__ b2, float* __restrict__ out, int N) {
    int i = blockIdx.x * blockDim.x + threadIdx.x;
    if (i >= N * 8) return;
    out[i] = acc2[i] / s2[i >> 3] + b2[i & 7];
}

// ---------------------------------------------------------------------------

extern "C" void kernel_launch(void* const* d_in, const int* in_sizes, int n_in,
                              void* d_out, int out_size, void* d_ws, size_t ws_size,
                              hipStream_t stream) {
    const float* x   = (const float*)d_in[0];
    const int*   ei  = (const int*)d_in[1];
    const float* W1  = (const float*)d_in[2];
    const float* as1 = (const float*)d_in[3];
    const float* ad1 = (const float*)d_in[4];
    const float* b1  = (const float*)d_in[5];
    const float* W2  = (const float*)d_in[6];
    const float* as2 = (const float*)d_in[7];
    const float* ad2 = (const float*)d_in[8];
    const float* b2  = (const float*)d_in[9];
    float* out = (float*)d_out;

    const int N = in_sizes[0];          // 100000
    const int E = in_sizes[1] / 2;      // 3200000
    const int NBK = (N + 63) >> 6;      // 1563 buckets of 64 nodes

    float* ws = (float*)d_ws;
    size_t need = (size_t)(16 + 3 * 2048 + 10 * (size_t)N + (size_t)E) * sizeof(float);

    if (N <= 131072 && ws_size >= need) {
        float*    consts  = ws;                          // 16
        int*      gcnt    = (int*)(ws + 16);             // 2048
        int*      gbase   = gcnt + 2048;                 // 2048
        int*      gcursor = gbase + 2048;                // 2048
        float*    als2    = ws + 16 + 3 * 2048;          // N
        float*    ald2    = als2 + N;                    // N
        float*    h2      = ald2 + N;                    // 8N
        unsigned* pairs   = (unsigned*)(h2 + 8 * (size_t)N);  // E

        hipMemsetAsync(gcnt, 0, 2048 * sizeof(int), stream);
        prep_consts<<<1, 64, 0, stream>>>(W1, as1, ad1, consts);
        bucket_hist<<<128, 256, 0, stream>>>(ei, gcnt, E);
        scan_init<<<1, 512, 0, stream>>>(gcnt, gbase, gcursor);
        bucket_scatter<<<256, 1024, 0, stream>>>(ei, gcursor, pairs, E);
        l1_seg<<<NBK, 256, 0, stream>>>(x, gbase, gcnt, pairs, consts,
                                        W1, b1, W2, as2, ad2, h2, als2, ald2, N);
        l2_seg<<<NBK, 256, 0, stream>>>(gbase, gcnt, pairs, als2, ald2, h2, b2, out, N);
    } else {
        // fallback: R2 atomic path (10.8 MB ws, known-correct)
        float* consts = ws;
        float* s1   = ws + 16;
        float* t1   = s1 + 4 * (size_t)N;
        float* h2   = t1 + 4 * (size_t)N;
        float* als2 = h2 + 8 * (size_t)N;
        float* ald2 = als2 + (size_t)N;
        float* s2   = ald2 + (size_t)N;
        float* acc2 = s2 + (size_t)N;

        hipMemsetAsync(ws, 0, (16 + 8 * (size_t)N) * sizeof(float), stream);
        hipMemsetAsync(s2, 0, 9 * (size_t)N * sizeof(float), stream);
        prep_consts<<<1, 64, 0, stream>>>(W1, as1, ad1, consts);
        int total = E + N;
        edge_pass1<<<(total + 255) / 256, 256, 0, stream>>>(ei, x, consts, s1, t1, E, N);
        node_mid<<<(N + 255) / 256, 256, 0, stream>>>(s1, t1, W1, b1, W2, as2, ad2, h2, als2, ald2, N);
        edge_pass2<<<(total + 255) / 256, 256, 0, stream>>>(ei, als2, ald2, h2, s2, acc2, E, N);
        node_out<<<(N * 8 + 255) / 256, 256, 0, stream>>>(s2, acc2, b2, out, N);
    }
}

// Round 8
// 223.821 us; speedup vs baseline: 2.1646x; 2.1646x over previous
//
#include <hip/hip_runtime.h>
#include <hip/hip_bf16.h>

#define NEG_SLOPE 0.2f

// ---------------------------------------------------------------------------
// GAT 2-layer, N=100k, E=3.2M (+self-loops handled analytically per node).
//
// R8: R7 pipeline kept (64-node bucket sort, private contiguous segments),
// but the aggregation kernels replace per-edge LDS atomicAdd with
// rank-round plain RMW:
//   R4-R7 invariant: l2 ~172-195us regardless of occupancy/FETCH/ILP.
//   Model: 9 LDS atomics/edge x 3.3M edges = 29.7M atomic-lane-ops,
//   serialized ~3.5cyc each on the CU-shared LDS unit -> 414K cyc/CU,
//   matching measured duration exactly. Fix: within-wave match_any on the
//   6-bit local-dst key -> per-group ranks -> rounds r=0,1,..: lanes with
//   rank==r do plain (non-atomic) RMW into a WAVE-PRIVATE LDS region
//   (distinct rows within a round, in-order LDS pipe across rounds, disjoint
//   regions across waves -> race-free, zero atomics, bank-parallel b128 ops).
//
// Layer 1 collapses because IN==1 (h1 = x*W1 is rank-1):
//   logit_src[n,h]=x[n]*S1[h], logit_dst[n,h]=x[n]*D1[h],
//   out1[n,h,c]=W1[h,c]*t1[n,h]+b1. No softmax max-subtraction needed
//   (|logit| <~ 30, exp safe in fp32; verified R2-R7 absmax 9.8e-4).
//
// ws layout (4B units): unchanged from R7.
// Guards: N <= 131072 (17-bit src, NBK<=2048). Fallback: R2 atomic path.
// ---------------------------------------------------------------------------

__global__ void prep_consts(const float* __restrict__ W1,
                            const float* __restrict__ as1,
                            const float* __restrict__ ad1,
                            float* __restrict__ consts) {
    int t = threadIdx.x;
    if (t >= 8) return;
    int h = t & 3;
    const float* a = (t < 4) ? as1 : ad1;
    float s = 0.f;
    #pragma unroll
    for (int c = 0; c < 8; ++c)
        s += W1[h * 8 + c] * a[h * 8 + c];
    consts[t] = s;
}

__global__ void bucket_hist(const int* __restrict__ ei, int* __restrict__ gcnt, int E) {
    __shared__ int cnt[2048];
    int t = threadIdx.x;
    for (int i = t; i < 2048; i += 256) cnt[i] = 0;
    __syncthreads();
    int stride = gridDim.x * 256;
    for (int e = blockIdx.x * 256 + t; e < E; e += stride)
        atomicAdd(&cnt[ei[E + e] >> 6], 1);
    __syncthreads();
    for (int i = t; i < 2048; i += 256) {
        int c = cnt[i];
        if (c) atomicAdd(&gcnt[i], c);
    }
}

// single block, 512 threads; each owns 4 consecutive buckets (2048 total).
__global__ void scan_init(const int* __restrict__ gcnt,
                          int* __restrict__ gbase, int* __restrict__ gcursor) {
    __shared__ int buf[512];
    int t = threadIdx.x;
    int c0 = gcnt[t * 4], c1 = gcnt[t * 4 + 1], c2 = gcnt[t * 4 + 2], c3 = gcnt[t * 4 + 3];
    int sum = c0 + c1 + c2 + c3;
    buf[t] = sum;
    __syncthreads();
    for (int o = 1; o < 512; o <<= 1) {
        int add = (t >= o) ? buf[t - o] : 0;
        __syncthreads();
        buf[t] += add;
        __syncthreads();
    }
    int base = buf[t] - sum;                       // exclusive
    gbase[t * 4] = base;     gcursor[t * 4] = base;     base += c0;
    gbase[t * 4 + 1] = base; gcursor[t * 4 + 1] = base; base += c1;
    gbase[t * 4 + 2] = base; gcursor[t * 4 + 2] = base; base += c2;
    gbase[t * 4 + 3] = base; gcursor[t * 4 + 3] = base;
}

__global__ void bucket_scatter(const int* __restrict__ ei, int* __restrict__ gcursor,
                               unsigned int* __restrict__ pairs, int E) {
    __shared__ int cnt[2048];
    __shared__ int basel[2048];
    int t = threadIdx.x;
    int chunk = (E + gridDim.x - 1) / gridDim.x;
    int lo = blockIdx.x * chunk;
    int hi = min(E, lo + chunk);
    for (int i = t; i < 2048; i += 1024) cnt[i] = 0;
    __syncthreads();
    for (int e = lo + t; e < hi; e += 1024)
        atomicAdd(&cnt[ei[E + e] >> 6], 1);
    __syncthreads();
    for (int i = t; i < 2048; i += 1024) {
        int c = cnt[i];
        basel[i] = c ? atomicAdd(&gcursor[i], c) : 0;
        cnt[i] = 0;
    }
    __syncthreads();
    for (int e = lo + t; e < hi; e += 1024) {
        int s = ei[e];
        int d = ei[E + e];
        int bk = d >> 6;
        int loc = atomicAdd(&cnt[bk], 1);
        pairs[basel[bk] + loc] = (unsigned)s | ((unsigned)(d & 63) << 17);
    }
}

// Layer-1 aggregation + epilogue + W2 transform + layer-2 logits.
// One block per 64-node bucket; rank-round plain-RMW accumulation.
__global__ void l1_comb(const float* __restrict__ x,
                        const int* __restrict__ gbase, const int* __restrict__ gcnt,
                        const unsigned int* __restrict__ pairs,
                        const float* __restrict__ consts,
                        const float* __restrict__ W1, const float* __restrict__ b1,
                        const float* __restrict__ W2,
                        const float* __restrict__ as2, const float* __restrict__ ad2,
                        float* __restrict__ h2, float* __restrict__ als2,
                        float* __restrict__ ald2, int N) {
    __shared__ __align__(16) float R[4 * 64 * 8];  // wave-private: [0..3]=s1,[4..7]=t1
    __shared__ float xl[64];
    int t = threadIdx.x;
    int lane = t & 63;
    int bk = blockIdx.x;
    int node0 = bk << 6;
    int nw = min(64, N - node0);
    for (int i = t; i < 4 * 64 * 8; i += 256) R[i] = 0.f;
    if (t < nw) xl[t] = x[node0 + t];
    float S[4], D[4];
    #pragma unroll
    for (int h = 0; h < 4; ++h) { S[h] = consts[h]; D[h] = consts[4 + h]; }
    __syncthreads();
    float* wreg = &R[(t >> 6) * 512];
    int b = gbase[bk];
    int hi = b + gcnt[bk];
    for (int i = b + t; i < hi; i += 256) {
        unsigned p = pairs[i];
        int src = (int)(p & 131071u);
        int ld  = (int)(p >> 17);
        float xs = x[src];
        float xd = xl[ld];
        float w[4];
        #pragma unroll
        for (int h = 0; h < 4; ++h) {
            float v = xs * S[h] + xd * D[h];
            v = (v > 0.f) ? v : NEG_SLOPE * v;
            w[h] = __expf(v);
        }
        // match_any over 6-bit key ld
        unsigned long long mask = ~0ull;
        #pragma unroll
        for (int bit = 0; bit < 6; ++bit) {
            unsigned long long bb = __ballot((ld >> bit) & 1);
            mask &= ((ld >> bit) & 1) ? bb : ~bb;
        }
        mask &= __ballot(1);                       // drop inactive-lane phantoms
        int rank = __popcll(mask & ((1ull << lane) - 1ull));
        float* row = &wreg[ld * 8];
        for (int r = 0; r < 64; ++r) {
            if (__ballot(rank == r) == 0ull) break;
            if (rank == r) {
                row[0] += w[0]; row[1] += w[1]; row[2] += w[2]; row[3] += w[3];
                row[4] = fmaf(w[0], xs, row[4]); row[5] = fmaf(w[1], xs, row[5]);
                row[6] = fmaf(w[2], xs, row[6]); row[7] = fmaf(w[3], xs, row[7]);
            }
        }
    }
    __syncthreads();
    if (t < nw) {
        int n = node0 + t;
        float xn = xl[t];
        float o[8];
        #pragma unroll
        for (int c = 0; c < 8; ++c) o[c] = 0.f;
        #pragma unroll
        for (int h = 0; h < 4; ++h) {
            float v = xn * (S[h] + D[h]);           // self-loop term
            v = (v > 0.f) ? v : NEG_SLOPE * v;
            float ww = __expf(v);
            float s1 = R[t * 8 + h] + R[512 + t * 8 + h]
                     + R[1024 + t * 8 + h] + R[1536 + t * 8 + h] + ww;
            float t1 = R[t * 8 + 4 + h] + R[512 + t * 8 + 4 + h]
                     + R[1024 + t * 8 + 4 + h] + R[1536 + t * 8 + 4 + h] + ww * xn;
            float tt = t1 / s1;
            #pragma unroll
            for (int c = 0; c < 8; ++c) {
                float r = fmaxf(tt * W1[h * 8 + c] + b1[h * 8 + c], 0.f);
                #pragma unroll
                for (int c2 = 0; c2 < 8; ++c2) o[c2] += r * W2[(h * 8 + c) * 8 + c2];
            }
        }
        float as = 0.f, ad = 0.f;
        #pragma unroll
        for (int c = 0; c < 8; ++c) { as += o[c] * as2[c]; ad += o[c] * ad2[c]; }
        float4* hv = (float4*)&h2[(size_t)n * 8];
        hv[0] = make_float4(o[0], o[1], o[2], o[3]);
        hv[1] = make_float4(o[4], o[5], o[6], o[7]);
        als2[n] = as;
        ald2[n] = ad;
    }
}

// Layer-2 aggregation + output epilogue; rank-round plain-RMW accumulation.
__global__ void l2_comb(const int* __restrict__ gbase, const int* __restrict__ gcnt,
                        const unsigned int* __restrict__ pairs,
                        const float* __restrict__ als2, const float* __restrict__ ald2,
                        const float* __restrict__ h2, const float* __restrict__ b2,
                        float* __restrict__ out, int N) {
    __shared__ __align__(16) float R[4 * 64 * 12];  // rows: [0]=s2,[1..8]=acc, pad to 12
    __shared__ float adl[64];
    int t = threadIdx.x;
    int lane = t & 63;
    int bk = blockIdx.x;
    int node0 = bk << 6;
    int nw = min(64, N - node0);
    for (int i = t; i < 4 * 64 * 12; i += 256) R[i] = 0.f;
    if (t < nw) adl[t] = ald2[node0 + t];
    __syncthreads();
    float* wreg = &R[(t >> 6) * 768];
    int b = gbase[bk];
    int hi = b + gcnt[bk];
    for (int i = b + t; i < hi; i += 256) {
        unsigned p = pairs[i];
        int src = (int)(p & 131071u);
        int ld  = (int)(p >> 17);
        float a = als2[src];
        const float4* hv = (const float4*)&h2[(size_t)src * 8];
        float4 ha = hv[0], hb = hv[1];
        float v = a + adl[ld];
        v = (v > 0.f) ? v : NEG_SLOPE * v;
        float w = __expf(v);
        unsigned long long mask = ~0ull;
        #pragma unroll
        for (int bit = 0; bit < 6; ++bit) {
            unsigned long long bb = __ballot((ld >> bit) & 1);
            mask &= ((ld >> bit) & 1) ? bb : ~bb;
        }
        mask &= __ballot(1);
        int rank = __popcll(mask & ((1ull << lane) - 1ull));
        float* row = &wreg[ld * 12];
        for (int r = 0; r < 64; ++r) {
            if (__ballot(rank == r) == 0ull) break;
            if (rank == r) {
                row[0] += w;
                row[1] = fmaf(w, ha.x, row[1]); row[2] = fmaf(w, ha.y, row[2]);
                row[3] = fmaf(w, ha.z, row[3]); row[4] = fmaf(w, ha.w, row[4]);
                row[5] = fmaf(w, hb.x, row[5]); row[6] = fmaf(w, hb.y, row[6]);
                row[7] = fmaf(w, hb.z, row[7]); row[8] = fmaf(w, hb.w, row[8]);
            }
        }
    }
    __syncthreads();
    if (t < nw) {
        int n = node0 + t;
        float v = als2[n] + adl[t];               // self-loop
        v = (v > 0.f) ? v : NEG_SLOPE * v;
        float ww = __expf(v);
        const float4* hv = (const float4*)&h2[(size_t)n * 8];
        float4 ha0 = hv[0], hb0 = hv[1];
        float acc[9];
        #pragma unroll
        for (int c = 0; c < 9; ++c)
            acc[c] = R[t * 12 + c] + R[768 + t * 12 + c]
                   + R[1536 + t * 12 + c] + R[2304 + t * 12 + c];
        float s2 = acc[0] + ww;
        float inv = 1.f / s2;
        float4* ov = (float4*)&out[(size_t)n * 8];
        ov[0] = make_float4((acc[1] + ww * ha0.x) * inv + b2[0],
                            (acc[2] + ww * ha0.y) * inv + b2[1],
                            (acc[3] + ww * ha0.z) * inv + b2[2],
                            (acc[4] + ww * ha0.w) * inv + b2[3]);
        ov[1] = make_float4((acc[5] + ww * hb0.x) * inv + b2[4],
                            (acc[6] + ww * hb0.y) * inv + b2[5],
                            (acc[7] + ww * hb0.z) * inv + b2[6],
                            (acc[8] + ww * hb0.w) * inv + b2[7]);
    }
}

// ---------------- fallback path (R2, atomic-based; known-correct) ----------------

__global__ void edge_pass1(const int* __restrict__ ei, const float* __restrict__ x,
                           const float* __restrict__ consts,
                           float* __restrict__ s1, float* __restrict__ t1, int E, int N) {
    int e = blockIdx.x * blockDim.x + threadIdx.x;
    if (e >= E + N) return;
    int src, dst;
    if (e < E) { src = ei[e]; dst = ei[E + e]; }
    else       { src = dst = e - E; }
    float xs = x[src], xd = x[dst];
    #pragma unroll
    for (int h = 0; h < 4; ++h) {
        float v = xs * consts[h] + xd * consts[4 + h];
        v = (v > 0.f) ? v : NEG_SLOPE * v;
        float w = __expf(v);
        atomicAdd(&s1[dst * 4 + h], w);
        atomicAdd(&t1[dst * 4 + h], w * xs);
    }
}

__global__ void node_mid(const float* __restrict__ s1, const float* __restrict__ t1,
                         const float* __restrict__ W1, const float* __restrict__ b1,
                         const float* __restrict__ W2,
                         const float* __restrict__ as2, const float* __restrict__ ad2,
                         float* __restrict__ h2, float* __restrict__ als2,
                         float* __restrict__ ald2, int N) {
    int n = blockIdx.x * blockDim.x + threadIdx.x;
    if (n >= N) return;
    float o[8];
    #pragma unroll
    for (int c = 0; c < 8; ++c) o[c] = 0.f;
    #pragma unroll
    for (int h = 0; h < 4; ++h) {
        float t = t1[n * 4 + h] / s1[n * 4 + h];
        #pragma unroll
        for (int c = 0; c < 8; ++c) {
            float r = fmaxf(t * W1[h * 8 + c] + b1[h * 8 + c], 0.f);
            #pragma unroll
            for (int c2 = 0; c2 < 8; ++c2) o[c2] += r * W2[(h * 8 + c) * 8 + c2];
        }
    }
    float as = 0.f, ad = 0.f;
    #pragma unroll
    for (int c = 0; c < 8; ++c) { h2[n * 8 + c] = o[c]; as += o[c] * as2[c]; ad += o[c] * ad2[c]; }
    als2[n] = as; ald2[n] = ad;
}

__global__ void edge_pass2(const int* __restrict__ ei, const float* __restrict__ als2,
                           const float* __restrict__ ald2, const float* __restrict__ h2,
                           float* __restrict__ s2, float* __restrict__ acc2, int E, int N) {
    int e = blockIdx.x * blockDim.x + threadIdx.x;
    if (e >= E + N) return;
    int src, dst;
    if (e < E) { src = ei[e]; dst = ei[E + e]; }
    else       { src = dst = e - E; }
    float v = als2[src] + ald2[dst];
    v = (v > 0.f) ? v : NEG_SLOPE * v;
    float w = __expf(v);
    atomicAdd(&s2[dst], w);
    const float4* hs = (const float4*)&h2[src * 8];
    float4 a = hs[0], bq = hs[1];
    float* acc = &acc2[dst * 8];
    atomicAdd(&acc[0], w * a.x);  atomicAdd(&acc[1], w * a.y);
    atomicAdd(&acc[2], w * a.z);  atomicAdd(&acc[3], w * a.w);
    atomicAdd(&acc[4], w * bq.x); atomicAdd(&acc[5], w * bq.y);
    atomicAdd(&acc[6], w * bq.z); atomicAdd(&acc[7], w * bq.w);
}

__global__ void node_out(const float* __restrict__ s2, const float* __restrict__ acc2,
                         const float* __restrict__ b2, float* __restrict__ out, int N) {
    int i = blockIdx.x * blockDim.x + threadIdx.x;
    if (i >= N * 8) return;
    out[i] = acc2[i] / s2[i >> 3] + b2[i & 7];
}

// ---------------------------------------------------------------------------

extern "C" void kernel_launch(void* const* d_in, const int* in_sizes, int n_in,
                              void* d_out, int out_size, void* d_ws, size_t ws_size,
                              hipStream_t stream) {
    const float* x   = (const float*)d_in[0];
    const int*   ei  = (const int*)d_in[1];
    const float* W1  = (const float*)d_in[2];
    const float* as1 = (const float*)d_in[3];
    const float* ad1 = (const float*)d_in[4];
    const float* b1  = (const float*)d_in[5];
    const float* W2  = (const float*)d_in[6];
    const float* as2 = (const float*)d_in[7];
    const float* ad2 = (const float*)d_in[8];
    const float* b2  = (const float*)d_in[9];
    float* out = (float*)d_out;

    const int N = in_sizes[0];          // 100000
    const int E = in_sizes[1] / 2;      // 3200000
    const int NBK = (N + 63) >> 6;      // 1563 buckets of 64 nodes

    float* ws = (float*)d_ws;
    size_t need = (size_t)(16 + 3 * 2048 + 10 * (size_t)N + (size_t)E) * sizeof(float);

    if (N <= 131072 && ws_size >= need) {
        float*    consts  = ws;                          // 16
        int*      gcnt    = (int*)(ws + 16);             // 2048
        int*      gbase   = gcnt + 2048;                 // 2048
        int*      gcursor = gbase + 2048;                // 2048
        float*    als2    = ws + 16 + 3 * 2048;          // N
        float*    ald2    = als2 + N;                    // N
        float*    h2      = ald2 + N;                    // 8N
        unsigned* pairs   = (unsigned*)(h2 + 8 * (size_t)N);  // E

        hipMemsetAsync(gcnt, 0, 2048 * sizeof(int), stream);
        prep_consts<<<1, 64, 0, stream>>>(W1, as1, ad1, consts);
        bucket_hist<<<128, 256, 0, stream>>>(ei, gcnt, E);
        scan_init<<<1, 512, 0, stream>>>(gcnt, gbase, gcursor);
        bucket_scatter<<<256, 1024, 0, stream>>>(ei, gcursor, pairs, E);
        l1_comb<<<NBK, 256, 0, stream>>>(x, gbase, gcnt, pairs, consts,
                                         W1, b1, W2, as2, ad2, h2, als2, ald2, N);
        l2_comb<<<NBK, 256, 0, stream>>>(gbase, gcnt, pairs, als2, ald2, h2, b2, out, N);
    } else {
        // fallback: R2 atomic path (10.8 MB ws, known-correct)
        float* consts = ws;
        float* s1   = ws + 16;
        float* t1   = s1 + 4 * (size_t)N;
        float* h2   = t1 + 4 * (size_t)N;
        float* als2 = h2 + 8 * (size_t)N;
        float* ald2 = als2 + (size_t)N;
        float* s2   = ald2 + (size_t)N;
        float* acc2 = s2 + (size_t)N;

        hipMemsetAsync(ws, 0, (16 + 8 * (size_t)N) * sizeof(float), stream);
        hipMemsetAsync(s2, 0, 9 * (size_t)N * sizeof(float), stream);
        prep_consts<<<1, 64, 0, stream>>>(W1, as1, ad1, consts);
        int total = E + N;
        edge_pass1<<<(total + 255) / 256, 256, 0, stream>>>(ei, x, consts, s1, t1, E, N);
        node_mid<<<(N + 255) / 256, 256, 0, stream>>>(s1, t1, W1, b1, W2, as2, ad2, h2, als2, ald2, N);
        edge_pass2<<<(total + 255) / 256, 256, 0, stream>>>(ei, als2, ald2, h2, s2, acc2, E, N);
        node_out<<<(N * 8 + 255) / 256, 256, 0, stream>>>(s2, acc2, b2, out, N);
    }
}

// Round 9
// 200.587 us; speedup vs baseline: 2.4154x; 1.1158x over previous
//
#include <hip/hip_runtime.h>
#include <hip/hip_bf16.h>

#define NEG_SLOPE 0.2f

// ---------------------------------------------------------------------------
// GAT 2-layer, N=100k, E=3.2M (+self-loops handled analytically per node).
//
// R9 (on top of R8's rank-round plain-RMW aggregation win, 484->224us):
//   - bucket_hist: 256 blocks (R8 used 128 -> half the CUs idle) + int4 loads
//   - bucket_scatter: int4 loads in phases 1 and 3 (1/4 issue work)
//   - l1/l2: 512 threads (8 waves -> 2x gather TLP), software-pipelined
//     next-pair prefetch; accumulation scheme unchanged
//   - prep_consts folded into scan_init
//
// R8 core idea (kept): within-wave match_any on the 6-bit local-dst key ->
// per-group ranks -> rounds: lanes with rank==r do plain (non-atomic) RMW
// into a WAVE-PRIVATE LDS region. Race-free, zero LDS atomics.
//
// Layer 1 collapses because IN==1 (h1 = x*W1 is rank-1); softmax without
// max-subtraction (|logit| <~ 30; verified R2-R8 absmax 9.8e-4).
//
// ws layout (4B units): unchanged from R7/R8.
// Guards: N <= 131072 (17-bit src, NBK<=2048). Fallback: R2 atomic path.
// ---------------------------------------------------------------------------

__global__ void bucket_hist(const int* __restrict__ ei, int* __restrict__ gcnt, int E) {
    __shared__ int cnt[2048];
    int t = threadIdx.x;
    for (int i = t; i < 2048; i += 256) cnt[i] = 0;
    __syncthreads();
    const int* dei = ei + E;
    int gid = blockIdx.x * 256 + t;
    int gstride = gridDim.x * 256;
    if ((E & 3) == 0) {
        const int4* dei4 = (const int4*)dei;
        int E4 = E >> 2;
        for (int v = gid; v < E4; v += gstride) {
            int4 d = dei4[v];
            atomicAdd(&cnt[d.x >> 6], 1);
            atomicAdd(&cnt[d.y >> 6], 1);
            atomicAdd(&cnt[d.z >> 6], 1);
            atomicAdd(&cnt[d.w >> 6], 1);
        }
    } else {
        for (int e = gid; e < E; e += gstride)
            atomicAdd(&cnt[dei[e] >> 6], 1);
    }
    __syncthreads();
    for (int i = t; i < 2048; i += 256) {
        int c = cnt[i];
        if (c) atomicAdd(&gcnt[i], c);
    }
}

// single block, 512 threads; consts + exclusive scan of 2048 bucket counts.
__global__ void scan_init(const int* __restrict__ gcnt,
                          int* __restrict__ gbase, int* __restrict__ gcursor,
                          const float* __restrict__ W1,
                          const float* __restrict__ as1,
                          const float* __restrict__ ad1,
                          float* __restrict__ consts) {
    __shared__ int buf[512];
    int t = threadIdx.x;
    if (t < 8) {
        int h = t & 3;
        const float* a = (t < 4) ? as1 : ad1;
        float s = 0.f;
        #pragma unroll
        for (int c = 0; c < 8; ++c)
            s += W1[h * 8 + c] * a[h * 8 + c];
        consts[t] = s;
    }
    int c0 = gcnt[t * 4], c1 = gcnt[t * 4 + 1], c2 = gcnt[t * 4 + 2], c3 = gcnt[t * 4 + 3];
    int sum = c0 + c1 + c2 + c3;
    buf[t] = sum;
    __syncthreads();
    for (int o = 1; o < 512; o <<= 1) {
        int add = (t >= o) ? buf[t - o] : 0;
        __syncthreads();
        buf[t] += add;
        __syncthreads();
    }
    int base = buf[t] - sum;                       // exclusive
    gbase[t * 4] = base;     gcursor[t * 4] = base;     base += c0;
    gbase[t * 4 + 1] = base; gcursor[t * 4 + 1] = base; base += c1;
    gbase[t * 4 + 2] = base; gcursor[t * 4 + 2] = base; base += c2;
    gbase[t * 4 + 3] = base; gcursor[t * 4 + 3] = base;
}

__global__ void bucket_scatter(const int* __restrict__ ei, int* __restrict__ gcursor,
                               unsigned int* __restrict__ pairs, int E) {
    __shared__ int cnt[2048];
    __shared__ int basel[2048];
    int t = threadIdx.x;
    int chunk = (E + gridDim.x - 1) / gridDim.x;
    int lo = blockIdx.x * chunk;
    int hi = min(E, lo + chunk);
    const int* dei = ei + E;
    for (int i = t; i < 2048; i += 1024) cnt[i] = 0;
    __syncthreads();
    bool vec = ((E & 3) == 0);
    int lo4 = (lo + 3) & ~3;
    int end4 = hi & ~3;
    if (vec && end4 > lo4) {
        // scalar head
        for (int e = lo + t; e < lo4; e += 1024)
            atomicAdd(&cnt[dei[e] >> 6], 1);
        const int4* dei4 = (const int4*)dei;
        for (int v = (lo4 >> 2) + t; v < (end4 >> 2); v += 1024) {
            int4 d = dei4[v];
            atomicAdd(&cnt[d.x >> 6], 1);
            atomicAdd(&cnt[d.y >> 6], 1);
            atomicAdd(&cnt[d.z >> 6], 1);
            atomicAdd(&cnt[d.w >> 6], 1);
        }
        for (int e = end4 + t; e < hi; e += 1024)
            atomicAdd(&cnt[dei[e] >> 6], 1);
    } else {
        for (int e = lo + t; e < hi; e += 1024)
            atomicAdd(&cnt[dei[e] >> 6], 1);
    }
    __syncthreads();
    for (int i = t; i < 2048; i += 1024) {
        int c = cnt[i];
        basel[i] = c ? atomicAdd(&gcursor[i], c) : 0;
        cnt[i] = 0;
    }
    __syncthreads();
    if (vec && end4 > lo4) {
        for (int e = lo + t; e < lo4; e += 1024) {
            int s = ei[e], d = dei[e];
            int bk = d >> 6;
            int loc = atomicAdd(&cnt[bk], 1);
            pairs[basel[bk] + loc] = (unsigned)s | ((unsigned)(d & 63) << 17);
        }
        const int4* sei4 = (const int4*)ei;
        const int4* dei4 = (const int4*)dei;
        for (int v = (lo4 >> 2) + t; v < (end4 >> 2); v += 1024) {
            int4 sv = sei4[v];
            int4 dv = dei4[v];
            int bk0 = dv.x >> 6, bk1 = dv.y >> 6, bk2 = dv.z >> 6, bk3 = dv.w >> 6;
            int l0 = atomicAdd(&cnt[bk0], 1);
            pairs[basel[bk0] + l0] = (unsigned)sv.x | ((unsigned)(dv.x & 63) << 17);
            int l1 = atomicAdd(&cnt[bk1], 1);
            pairs[basel[bk1] + l1] = (unsigned)sv.y | ((unsigned)(dv.y & 63) << 17);
            int l2 = atomicAdd(&cnt[bk2], 1);
            pairs[basel[bk2] + l2] = (unsigned)sv.z | ((unsigned)(dv.z & 63) << 17);
            int l3 = atomicAdd(&cnt[bk3], 1);
            pairs[basel[bk3] + l3] = (unsigned)sv.w | ((unsigned)(dv.w & 63) << 17);
        }
        for (int e = end4 + t; e < hi; e += 1024) {
            int s = ei[e], d = dei[e];
            int bk = d >> 6;
            int loc = atomicAdd(&cnt[bk], 1);
            pairs[basel[bk] + loc] = (unsigned)s | ((unsigned)(d & 63) << 17);
        }
    } else {
        for (int e = lo + t; e < hi; e += 1024) {
            int s = ei[e], d = dei[e];
            int bk = d >> 6;
            int loc = atomicAdd(&cnt[bk], 1);
            pairs[basel[bk] + loc] = (unsigned)s | ((unsigned)(d & 63) << 17);
        }
    }
}

// Layer-1 aggregation + epilogue + W2 transform + layer-2 logits.
// One block (512 thr = 8 waves) per 64-node bucket; rank-round plain RMW.
__global__ void l1_comb(const float* __restrict__ x,
                        const int* __restrict__ gbase, const int* __restrict__ gcnt,
                        const unsigned int* __restrict__ pairs,
                        const float* __restrict__ consts,
                        const float* __restrict__ W1, const float* __restrict__ b1,
                        const float* __restrict__ W2,
                        const float* __restrict__ as2, const float* __restrict__ ad2,
                        float* __restrict__ h2, float* __restrict__ als2,
                        float* __restrict__ ald2, int N) {
    __shared__ __align__(16) float R[8 * 64 * 8];  // wave-private: [0..3]=s1,[4..7]=t1
    __shared__ float xl[64];
    int t = threadIdx.x;
    int lane = t & 63;
    int bk = blockIdx.x;
    int node0 = bk << 6;
    int nw = min(64, N - node0);
    for (int i = t; i < 8 * 64 * 8; i += 512) R[i] = 0.f;
    if (t < nw) xl[t] = x[node0 + t];
    float S[4], D[4];
    #pragma unroll
    for (int h = 0; h < 4; ++h) { S[h] = consts[h]; D[h] = consts[4 + h]; }
    __syncthreads();
    float* wreg = &R[(t >> 6) * 512];
    int b = gbase[bk];
    int hi = b + gcnt[bk];
    int i = b + t;
    unsigned p = (i < hi) ? pairs[i] : 0u;
    while (i < hi) {
        int inx = i + 512;
        unsigned pn = 0u;
        if (inx < hi) pn = pairs[inx];          // prefetch next iteration's pair
        int src = (int)(p & 131071u);
        int ld  = (int)(p >> 17);
        float xs = x[src];
        float xd = xl[ld];
        float w[4];
        #pragma unroll
        for (int h = 0; h < 4; ++h) {
            float v = xs * S[h] + xd * D[h];
            v = (v > 0.f) ? v : NEG_SLOPE * v;
            w[h] = __expf(v);
        }
        unsigned long long mask = ~0ull;
        #pragma unroll
        for (int bit = 0; bit < 6; ++bit) {
            unsigned long long bb = __ballot((ld >> bit) & 1);
            mask &= ((ld >> bit) & 1) ? bb : ~bb;
        }
        mask &= __ballot(1);
        int rank = __popcll(mask & ((1ull << lane) - 1ull));
        float* row = &wreg[ld * 8];
        for (int r = 0; r < 64; ++r) {
            if (__ballot(rank == r) == 0ull) break;
            if (rank == r) {
                row[0] += w[0]; row[1] += w[1]; row[2] += w[2]; row[3] += w[3];
                row[4] = fmaf(w[0], xs, row[4]); row[5] = fmaf(w[1], xs, row[5]);
                row[6] = fmaf(w[2], xs, row[6]); row[7] = fmaf(w[3], xs, row[7]);
            }
        }
        p = pn; i = inx;
    }
    __syncthreads();
    if (t < nw) {
        int n = node0 + t;
        float xn = xl[t];
        float o[8];
        #pragma unroll
        for (int c = 0; c < 8; ++c) o[c] = 0.f;
        #pragma unroll
        for (int h = 0; h < 4; ++h) {
            float v = xn * (S[h] + D[h]);           // self-loop term
            v = (v > 0.f) ? v : NEG_SLOPE * v;
            float ww = __expf(v);
            float s1 = ww, t1 = ww * xn;
            #pragma unroll
            for (int r = 0; r < 8; ++r) {
                s1 += R[r * 512 + t * 8 + h];
                t1 += R[r * 512 + t * 8 + 4 + h];
            }
            float tt = t1 / s1;
            #pragma unroll
            for (int c = 0; c < 8; ++c) {
                float rr = fmaxf(tt * W1[h * 8 + c] + b1[h * 8 + c], 0.f);
                #pragma unroll
                for (int c2 = 0; c2 < 8; ++c2) o[c2] += rr * W2[(h * 8 + c) * 8 + c2];
            }
        }
        float as = 0.f, ad = 0.f;
        #pragma unroll
        for (int c = 0; c < 8; ++c) { as += o[c] * as2[c]; ad += o[c] * ad2[c]; }
        float4* hv = (float4*)&h2[(size_t)n * 8];
        hv[0] = make_float4(o[0], o[1], o[2], o[3]);
        hv[1] = make_float4(o[4], o[5], o[6], o[7]);
        als2[n] = as;
        ald2[n] = ad;
    }
}

// Layer-2 aggregation + output epilogue; 512 thr, rank-round plain RMW.
__global__ void l2_comb(const int* __restrict__ gbase, const int* __restrict__ gcnt,
                        const unsigned int* __restrict__ pairs,
                        const float* __restrict__ als2, const float* __restrict__ ald2,
                        const float* __restrict__ h2, const float* __restrict__ b2,
                        float* __restrict__ out, int N) {
    __shared__ __align__(16) float R[8 * 64 * 12];  // rows: [0]=s2,[1..8]=acc, pad 12
    __shared__ float adl[64];
    int t = threadIdx.x;
    int lane = t & 63;
    int bk = blockIdx.x;
    int node0 = bk << 6;
    int nw = min(64, N - node0);
    for (int i = t; i < 8 * 64 * 12; i += 512) R[i] = 0.f;
    if (t < nw) adl[t] = ald2[node0 + t];
    __syncthreads();
    float* wreg = &R[(t >> 6) * 768];
    int b = gbase[bk];
    int hi = b + gcnt[bk];
    int i = b + t;
    unsigned p = (i < hi) ? pairs[i] : 0u;
    while (i < hi) {
        int inx = i + 512;
        unsigned pn = 0u;
        if (inx < hi) pn = pairs[inx];          // prefetch
        int src = (int)(p & 131071u);
        int ld  = (int)(p >> 17);
        float a = als2[src];
        const float4* hv = (const float4*)&h2[(size_t)src * 8];
        float4 ha = hv[0], hb = hv[1];
        float v = a + adl[ld];
        v = (v > 0.f) ? v : NEG_SLOPE * v;
        float w = __expf(v);
        unsigned long long mask = ~0ull;
        #pragma unroll
        for (int bit = 0; bit < 6; ++bit) {
            unsigned long long bb = __ballot((ld >> bit) & 1);
            mask &= ((ld >> bit) & 1) ? bb : ~bb;
        }
        mask &= __ballot(1);
        int rank = __popcll(mask & ((1ull << lane) - 1ull));
        float* row = &wreg[ld * 12];
        for (int r = 0; r < 64; ++r) {
            if (__ballot(rank == r) == 0ull) break;
            if (rank == r) {
                row[0] += w;
                row[1] = fmaf(w, ha.x, row[1]); row[2] = fmaf(w, ha.y, row[2]);
                row[3] = fmaf(w, ha.z, row[3]); row[4] = fmaf(w, ha.w, row[4]);
                row[5] = fmaf(w, hb.x, row[5]); row[6] = fmaf(w, hb.y, row[6]);
                row[7] = fmaf(w, hb.z, row[7]); row[8] = fmaf(w, hb.w, row[8]);
            }
        }
        p = pn; i = inx;
    }
    __syncthreads();
    if (t < nw) {
        int n = node0 + t;
        float v = als2[n] + adl[t];               // self-loop
        v = (v > 0.f) ? v : NEG_SLOPE * v;
        float ww = __expf(v);
        const float4* hv = (const float4*)&h2[(size_t)n * 8];
        float4 ha0 = hv[0], hb0 = hv[1];
        float acc[9];
        #pragma unroll
        for (int c = 0; c < 9; ++c) {
            float s = 0.f;
            #pragma unroll
            for (int r = 0; r < 8; ++r) s += R[r * 768 + t * 12 + c];
            acc[c] = s;
        }
        float s2 = acc[0] + ww;
        float inv = 1.f / s2;
        float4* ov = (float4*)&out[(size_t)n * 8];
        ov[0] = make_float4((acc[1] + ww * ha0.x) * inv + b2[0],
                            (acc[2] + ww * ha0.y) * inv + b2[1],
                            (acc[3] + ww * ha0.z) * inv + b2[2],
                            (acc[4] + ww * ha0.w) * inv + b2[3]);
        ov[1] = make_float4((acc[5] + ww * hb0.x) * inv + b2[4],
                            (acc[6] + ww * hb0.y) * inv + b2[5],
                            (acc[7] + ww * hb0.z) * inv + b2[6],
                            (acc[8] + ww * hb0.w) * inv + b2[7]);
    }
}

// ---------------- fallback path (R2, atomic-based; known-correct) ----------------

__global__ void prep_consts(const float* __restrict__ W1,
                            const float* __restrict__ as1,
                            const float* __restrict__ ad1,
                            float* __restrict__ consts) {
    int t = threadIdx.x;
    if (t >= 8) return;
    int h = t & 3;
    const float* a = (t < 4) ? as1 : ad1;
    float s = 0.f;
    #pragma unroll
    for (int c = 0; c < 8; ++c)
        s += W1[h * 8 + c] * a[h * 8 + c];
    consts[t] = s;
}

__global__ void edge_pass1(const int* __restrict__ ei, const float* __restrict__ x,
                           const float* __restrict__ consts,
                           float* __restrict__ s1, float* __restrict__ t1, int E, int N) {
    int e = blockIdx.x * blockDim.x + threadIdx.x;
    if (e >= E + N) return;
    int src, dst;
    if (e < E) { src = ei[e]; dst = ei[E + e]; }
    else       { src = dst = e - E; }
    float xs = x[src], xd = x[dst];
    #pragma unroll
    for (int h = 0; h < 4; ++h) {
        float v = xs * consts[h] + xd * consts[4 + h];
        v = (v > 0.f) ? v : NEG_SLOPE * v;
        float w = __expf(v);
        atomicAdd(&s1[dst * 4 + h], w);
        atomicAdd(&t1[dst * 4 + h], w * xs);
    }
}

__global__ void node_mid(const float* __restrict__ s1, const float* __restrict__ t1,
                         const float* __restrict__ W1, const float* __restrict__ b1,
                         const float* __restrict__ W2,
                         const float* __restrict__ as2, const float* __restrict__ ad2,
                         float* __restrict__ h2, float* __restrict__ als2,
                         float* __restrict__ ald2, int N) {
    int n = blockIdx.x * blockDim.x + threadIdx.x;
    if (n >= N) return;
    float o[8];
    #pragma unroll
    for (int c = 0; c < 8; ++c) o[c] = 0.f;
    #pragma unroll
    for (int h = 0; h < 4; ++h) {
        float t = t1[n * 4 + h] / s1[n * 4 + h];
        #pragma unroll
        for (int c = 0; c < 8; ++c) {
            float r = fmaxf(t * W1[h * 8 + c] + b1[h * 8 + c], 0.f);
            #pragma unroll
            for (int c2 = 0; c2 < 8; ++c2) o[c2] += r * W2[(h * 8 + c) * 8 + c2];
        }
    }
    float as = 0.f, ad = 0.f;
    #pragma unroll
    for (int c = 0; c < 8; ++c) { h2[n * 8 + c] = o[c]; as += o[c] * as2[c]; ad += o[c] * ad2[c]; }
    als2[n] = as; ald2[n] = ad;
}

__global__ void edge_pass2(const int* __restrict__ ei, const float* __restrict__ als2,
                           const float* __restrict__ ald2, const float* __restrict__ h2,
                           float* __restrict__ s2, float* __restrict__ acc2, int E, int N) {
    int e = blockIdx.x * blockDim.x + threadIdx.x;
    if (e >= E + N) return;
    int src, dst;
    if (e < E) { src = ei[e]; dst = ei[E + e]; }
    else       { src = dst = e - E; }
    float v = als2[src] + ald2[dst];
    v = (v > 0.f) ? v : NEG_SLOPE * v;
    float w = __expf(v);
    atomicAdd(&s2[dst], w);
    const float4* hs = (const float4*)&h2[src * 8];
    float4 a = hs[0], bq = hs[1];
    float* acc = &acc2[dst * 8];
    atomicAdd(&acc[0], w * a.x);  atomicAdd(&acc[1], w * a.y);
    atomicAdd(&acc[2], w * a.z);  atomicAdd(&acc[3], w * a.w);
    atomicAdd(&acc[4], w * bq.x); atomicAdd(&acc[5], w * bq.y);
    atomicAdd(&acc[6], w * bq.z); atomicAdd(&acc[7], w * bq.w);
}

__global__ void node_out(const float* __restrict__ s2, const float* __restrict__ acc2,
                         const float* __restrict__ b2, float* __restrict__ out, int N) {
    int i = blockIdx.x * blockDim.x + threadIdx.x;
    if (i >= N * 8) return;
    out[i] = acc2[i] / s2[i >> 3] + b2[i & 7];
}

// ---------------------------------------------------------------------------

extern "C" void kernel_launch(void* const* d_in, const int* in_sizes, int n_in,
                              void* d_out, int out_size, void* d_ws, size_t ws_size,
                              hipStream_t stream) {
    const float* x   = (const float*)d_in[0];
    const int*   ei  = (const int*)d_in[1];
    const float* W1  = (const float*)d_in[2];
    const float* as1 = (const float*)d_in[3];
    const float* ad1 = (const float*)d_in[4];
    const float* b1  = (const float*)d_in[5];
    const float* W2  = (const float*)d_in[6];
    const float* as2 = (const float*)d_in[7];
    const float* ad2 = (const float*)d_in[8];
    const float* b2  = (const float*)d_in[9];
    float* out = (float*)d_out;

    const int N = in_sizes[0];          // 100000
    const int E = in_sizes[1] / 2;      // 3200000
    const int NBK = (N + 63) >> 6;      // 1563 buckets of 64 nodes

    float* ws = (float*)d_ws;
    size_t need = (size_t)(16 + 3 * 2048 + 10 * (size_t)N + (size_t)E) * sizeof(float);

    if (N <= 131072 && ws_size >= need) {
        float*    consts  = ws;                          // 16
        int*      gcnt    = (int*)(ws + 16);             // 2048
        int*      gbase   = gcnt + 2048;                 // 2048
        int*      gcursor = gbase + 2048;                // 2048
        float*    als2    = ws + 16 + 3 * 2048;          // N
        float*    ald2    = als2 + N;                    // N
        float*    h2      = ald2 + N;                    // 8N
        unsigned* pairs   = (unsigned*)(h2 + 8 * (size_t)N);  // E

        hipMemsetAsync(gcnt, 0, 2048 * sizeof(int), stream);
        bucket_hist<<<256, 256, 0, stream>>>(ei, gcnt, E);
        scan_init<<<1, 512, 0, stream>>>(gcnt, gbase, gcursor, W1, as1, ad1, consts);
        bucket_scatter<<<256, 1024, 0, stream>>>(ei, gcursor, pairs, E);
        l1_comb<<<NBK, 512, 0, stream>>>(x, gbase, gcnt, pairs, consts,
                                         W1, b1, W2, as2, ad2, h2, als2, ald2, N);
        l2_comb<<<NBK, 512, 0, stream>>>(gbase, gcnt, pairs, als2, ald2, h2, b2, out, N);
    } else {
        // fallback: R2 atomic path (10.8 MB ws, known-correct)
        float* consts = ws;
        float* s1   = ws + 16;
        float* t1   = s1 + 4 * (size_t)N;
        float* h2   = t1 + 4 * (size_t)N;
        float* als2 = h2 + 8 * (size_t)N;
        float* ald2 = als2 + (size_t)N;
        float* s2   = ald2 + (size_t)N;
        float* acc2 = s2 + (size_t)N;

        hipMemsetAsync(ws, 0, (16 + 8 * (size_t)N) * sizeof(float), stream);
        hipMemsetAsync(s2, 0, 9 * (size_t)N * sizeof(float), stream);
        prep_consts<<<1, 64, 0, stream>>>(W1, as1, ad1, consts);
        int total = E + N;
        edge_pass1<<<(total + 255) / 256, 256, 0, stream>>>(ei, x, consts, s1, t1, E, N);
        node_mid<<<(N + 255) / 256, 256, 0, stream>>>(s1, t1, W1, b1, W2, as2, ad2, h2, als2, ald2, N);
        edge_pass2<<<(total + 255) / 256, 256, 0, stream>>>(ei, als2, ald2, h2, s2, acc2, E, N);
        node_out<<<(N * 8 + 255) / 256, 256, 0, stream>>>(s2, acc2, b2, out, N);
    }
}

// Round 10
// 200.468 us; speedup vs baseline: 2.4168x; 1.0006x over previous
//
#include <hip/hip_runtime.h>
#include <hip/hip_bf16.h>

#define NEG_SLOPE 0.2f

// ---------------------------------------------------------------------------
// GAT 2-layer, N=100k, E=3.2M (+self-loops handled analytically per node).
//
// R10: fix R9's self-inflicted LDS bank aliasing in the aggregation kernels.
// R9 counters: l2_comb SQ_LDS_BANK_CONFLICT 7.78M cyc (R7: 100K) — row
// stride 12 -> gcd(12,32)=4 -> 8 bank residues -> 8-way conflicts (l1 stride
// 8 -> 16-way). Fix: row stride 9 (odd -> all 32 banks, 2-way aliasing =
// free per m136). Scalar b32 RMW ops are bank-parallel and cheaper than the
// conflicted wide ops. Everything else unchanged from R9 (224->200us):
//   - bucket sort to 64-node buckets (hist int4 / scan / scatter int4)
//   - rank-round plain-RMW wave-private accumulation (R8's win: zero atomics)
//   - 512-thread aggregation blocks with next-pair prefetch
//
// Layer 1 collapses because IN==1 (h1 = x*W1 is rank-1); softmax without
// max-subtraction (|logit| <~ 30; verified R2-R9 absmax 9.8e-4).
//
// ws layout (4B units): unchanged from R7/R8/R9.
// Guards: N <= 131072 (17-bit src, NBK<=2048). Fallback: R2 atomic path.
// ---------------------------------------------------------------------------

__global__ void bucket_hist(const int* __restrict__ ei, int* __restrict__ gcnt, int E) {
    __shared__ int cnt[2048];
    int t = threadIdx.x;
    for (int i = t; i < 2048; i += 256) cnt[i] = 0;
    __syncthreads();
    const int* dei = ei + E;
    int gid = blockIdx.x * 256 + t;
    int gstride = gridDim.x * 256;
    if ((E & 3) == 0) {
        const int4* dei4 = (const int4*)dei;
        int E4 = E >> 2;
        for (int v = gid; v < E4; v += gstride) {
            int4 d = dei4[v];
            atomicAdd(&cnt[d.x >> 6], 1);
            atomicAdd(&cnt[d.y >> 6], 1);
            atomicAdd(&cnt[d.z >> 6], 1);
            atomicAdd(&cnt[d.w >> 6], 1);
        }
    } else {
        for (int e = gid; e < E; e += gstride)
            atomicAdd(&cnt[dei[e] >> 6], 1);
    }
    __syncthreads();
    for (int i = t; i < 2048; i += 256) {
        int c = cnt[i];
        if (c) atomicAdd(&gcnt[i], c);
    }
}

// single block, 512 threads; consts + exclusive scan of 2048 bucket counts.
__global__ void scan_init(const int* __restrict__ gcnt,
                          int* __restrict__ gbase, int* __restrict__ gcursor,
                          const float* __restrict__ W1,
                          const float* __restrict__ as1,
                          const float* __restrict__ ad1,
                          float* __restrict__ consts) {
    __shared__ int buf[512];
    int t = threadIdx.x;
    if (t < 8) {
        int h = t & 3;
        const float* a = (t < 4) ? as1 : ad1;
        float s = 0.f;
        #pragma unroll
        for (int c = 0; c < 8; ++c)
            s += W1[h * 8 + c] * a[h * 8 + c];
        consts[t] = s;
    }
    int c0 = gcnt[t * 4], c1 = gcnt[t * 4 + 1], c2 = gcnt[t * 4 + 2], c3 = gcnt[t * 4 + 3];
    int sum = c0 + c1 + c2 + c3;
    buf[t] = sum;
    __syncthreads();
    for (int o = 1; o < 512; o <<= 1) {
        int add = (t >= o) ? buf[t - o] : 0;
        __syncthreads();
        buf[t] += add;
        __syncthreads();
    }
    int base = buf[t] - sum;                       // exclusive
    gbase[t * 4] = base;     gcursor[t * 4] = base;     base += c0;
    gbase[t * 4 + 1] = base; gcursor[t * 4 + 1] = base; base += c1;
    gbase[t * 4 + 2] = base; gcursor[t * 4 + 2] = base; base += c2;
    gbase[t * 4 + 3] = base; gcursor[t * 4 + 3] = base;
}

__global__ void bucket_scatter(const int* __restrict__ ei, int* __restrict__ gcursor,
                               unsigned int* __restrict__ pairs, int E) {
    __shared__ int cnt[2048];
    __shared__ int basel[2048];
    int t = threadIdx.x;
    int chunk = (E + gridDim.x - 1) / gridDim.x;
    int lo = blockIdx.x * chunk;
    int hi = min(E, lo + chunk);
    const int* dei = ei + E;
    for (int i = t; i < 2048; i += 1024) cnt[i] = 0;
    __syncthreads();
    bool vec = ((E & 3) == 0);
    int lo4 = (lo + 3) & ~3;
    int end4 = hi & ~3;
    if (vec && end4 > lo4) {
        for (int e = lo + t; e < lo4; e += 1024)
            atomicAdd(&cnt[dei[e] >> 6], 1);
        const int4* dei4 = (const int4*)dei;
        for (int v = (lo4 >> 2) + t; v < (end4 >> 2); v += 1024) {
            int4 d = dei4[v];
            atomicAdd(&cnt[d.x >> 6], 1);
            atomicAdd(&cnt[d.y >> 6], 1);
            atomicAdd(&cnt[d.z >> 6], 1);
            atomicAdd(&cnt[d.w >> 6], 1);
        }
        for (int e = end4 + t; e < hi; e += 1024)
            atomicAdd(&cnt[dei[e] >> 6], 1);
    } else {
        for (int e = lo + t; e < hi; e += 1024)
            atomicAdd(&cnt[dei[e] >> 6], 1);
    }
    __syncthreads();
    for (int i = t; i < 2048; i += 1024) {
        int c = cnt[i];
        basel[i] = c ? atomicAdd(&gcursor[i], c) : 0;
        cnt[i] = 0;
    }
    __syncthreads();
    if (vec && end4 > lo4) {
        for (int e = lo + t; e < lo4; e += 1024) {
            int s = ei[e], d = dei[e];
            int bk = d >> 6;
            int loc = atomicAdd(&cnt[bk], 1);
            pairs[basel[bk] + loc] = (unsigned)s | ((unsigned)(d & 63) << 17);
        }
        const int4* sei4 = (const int4*)ei;
        const int4* dei4 = (const int4*)dei;
        for (int v = (lo4 >> 2) + t; v < (end4 >> 2); v += 1024) {
            int4 sv = sei4[v];
            int4 dv = dei4[v];
            int bk0 = dv.x >> 6, bk1 = dv.y >> 6, bk2 = dv.z >> 6, bk3 = dv.w >> 6;
            int l0 = atomicAdd(&cnt[bk0], 1);
            pairs[basel[bk0] + l0] = (unsigned)sv.x | ((unsigned)(dv.x & 63) << 17);
            int l1 = atomicAdd(&cnt[bk1], 1);
            pairs[basel[bk1] + l1] = (unsigned)sv.y | ((unsigned)(dv.y & 63) << 17);
            int l2 = atomicAdd(&cnt[bk2], 1);
            pairs[basel[bk2] + l2] = (unsigned)sv.z | ((unsigned)(dv.z & 63) << 17);
            int l3 = atomicAdd(&cnt[bk3], 1);
            pairs[basel[bk3] + l3] = (unsigned)sv.w | ((unsigned)(dv.w & 63) << 17);
        }
        for (int e = end4 + t; e < hi; e += 1024) {
            int s = ei[e], d = dei[e];
            int bk = d >> 6;
            int loc = atomicAdd(&cnt[bk], 1);
            pairs[basel[bk] + loc] = (unsigned)s | ((unsigned)(d & 63) << 17);
        }
    } else {
        for (int e = lo + t; e < hi; e += 1024) {
            int s = ei[e], d = dei[e];
            int bk = d >> 6;
            int loc = atomicAdd(&cnt[bk], 1);
            pairs[basel[bk] + loc] = (unsigned)s | ((unsigned)(d & 63) << 17);
        }
    }
}

// Layer-1 aggregation + epilogue + W2 transform + layer-2 logits.
// One block (512 thr = 8 waves) per 64-node bucket; rank-round plain RMW.
// Accumulator rows stride 9 (odd -> 2-way bank aliasing = free).
__global__ void l1_comb(const float* __restrict__ x,
                        const int* __restrict__ gbase, const int* __restrict__ gcnt,
                        const unsigned int* __restrict__ pairs,
                        const float* __restrict__ consts,
                        const float* __restrict__ W1, const float* __restrict__ b1,
                        const float* __restrict__ W2,
                        const float* __restrict__ as2, const float* __restrict__ ad2,
                        float* __restrict__ h2, float* __restrict__ als2,
                        float* __restrict__ ald2, int N) {
    __shared__ float R[8 * 64 * 9];   // wave-private rows: [0..3]=s1,[4..7]=t1, pad 1
    __shared__ float xl[64];
    int t = threadIdx.x;
    int lane = t & 63;
    int bk = blockIdx.x;
    int node0 = bk << 6;
    int nw = min(64, N - node0);
    for (int i = t; i < 8 * 64 * 9; i += 512) R[i] = 0.f;
    if (t < nw) xl[t] = x[node0 + t];
    float S[4], D[4];
    #pragma unroll
    for (int h = 0; h < 4; ++h) { S[h] = consts[h]; D[h] = consts[4 + h]; }
    __syncthreads();
    float* wreg = &R[(t >> 6) * 576];
    int b = gbase[bk];
    int hi = b + gcnt[bk];
    int i = b + t;
    unsigned p = (i < hi) ? pairs[i] : 0u;
    while (i < hi) {
        int inx = i + 512;
        unsigned pn = 0u;
        if (inx < hi) pn = pairs[inx];          // prefetch next iteration's pair
        int src = (int)(p & 131071u);
        int ld  = (int)(p >> 17);
        float xs = x[src];
        float xd = xl[ld];
        float w[4];
        #pragma unroll
        for (int h = 0; h < 4; ++h) {
            float v = xs * S[h] + xd * D[h];
            v = (v > 0.f) ? v : NEG_SLOPE * v;
            w[h] = __expf(v);
        }
        unsigned long long mask = ~0ull;
        #pragma unroll
        for (int bit = 0; bit < 6; ++bit) {
            unsigned long long bb = __ballot((ld >> bit) & 1);
            mask &= ((ld >> bit) & 1) ? bb : ~bb;
        }
        mask &= __ballot(1);
        int rank = __popcll(mask & ((1ull << lane) - 1ull));
        float* row = &wreg[ld * 9];
        for (int r = 0; r < 64; ++r) {
            if (__ballot(rank == r) == 0ull) break;
            if (rank == r) {
                row[0] += w[0]; row[1] += w[1]; row[2] += w[2]; row[3] += w[3];
                row[4] = fmaf(w[0], xs, row[4]); row[5] = fmaf(w[1], xs, row[5]);
                row[6] = fmaf(w[2], xs, row[6]); row[7] = fmaf(w[3], xs, row[7]);
            }
        }
        p = pn; i = inx;
    }
    __syncthreads();
    if (t < nw) {
        int n = node0 + t;
        float xn = xl[t];
        float o[8];
        #pragma unroll
        for (int c = 0; c < 8; ++c) o[c] = 0.f;
        #pragma unroll
        for (int h = 0; h < 4; ++h) {
            float v = xn * (S[h] + D[h]);           // self-loop term
            v = (v > 0.f) ? v : NEG_SLOPE * v;
            float ww = __expf(v);
            float s1 = ww, t1 = ww * xn;
            #pragma unroll
            for (int r = 0; r < 8; ++r) {
                s1 += R[r * 576 + t * 9 + h];
                t1 += R[r * 576 + t * 9 + 4 + h];
            }
            float tt = t1 / s1;
            #pragma unroll
            for (int c = 0; c < 8; ++c) {
                float rr = fmaxf(tt * W1[h * 8 + c] + b1[h * 8 + c], 0.f);
                #pragma unroll
                for (int c2 = 0; c2 < 8; ++c2) o[c2] += rr * W2[(h * 8 + c) * 8 + c2];
            }
        }
        float as = 0.f, ad = 0.f;
        #pragma unroll
        for (int c = 0; c < 8; ++c) { as += o[c] * as2[c]; ad += o[c] * ad2[c]; }
        float4* hv = (float4*)&h2[(size_t)n * 8];
        hv[0] = make_float4(o[0], o[1], o[2], o[3]);
        hv[1] = make_float4(o[4], o[5], o[6], o[7]);
        als2[n] = as;
        ald2[n] = ad;
    }
}

// Layer-2 aggregation + output epilogue; 512 thr, rank-round plain RMW.
// Accumulator rows stride 9 (exactly 9 values: s2 + 8 acc; odd -> free).
__global__ void l2_comb(const int* __restrict__ gbase, const int* __restrict__ gcnt,
                        const unsigned int* __restrict__ pairs,
                        const float* __restrict__ als2, const float* __restrict__ ald2,
                        const float* __restrict__ h2, const float* __restrict__ b2,
                        float* __restrict__ out, int N) {
    __shared__ float R[8 * 64 * 9];   // wave-private rows: [0]=s2, [1..8]=acc
    __shared__ float adl[64];
    int t = threadIdx.x;
    int lane = t & 63;
    int bk = blockIdx.x;
    int node0 = bk << 6;
    int nw = min(64, N - node0);
    for (int i = t; i < 8 * 64 * 9; i += 512) R[i] = 0.f;
    if (t < nw) adl[t] = ald2[node0 + t];
    __syncthreads();
    float* wreg = &R[(t >> 6) * 576];
    int b = gbase[bk];
    int hi = b + gcnt[bk];
    int i = b + t;
    unsigned p = (i < hi) ? pairs[i] : 0u;
    while (i < hi) {
        int inx = i + 512;
        unsigned pn = 0u;
        if (inx < hi) pn = pairs[inx];          // prefetch
        int src = (int)(p & 131071u);
        int ld  = (int)(p >> 17);
        float a = als2[src];
        const float4* hv = (const float4*)&h2[(size_t)src * 8];
        float4 ha = hv[0], hb = hv[1];
        float v = a + adl[ld];
        v = (v > 0.f) ? v : NEG_SLOPE * v;
        float w = __expf(v);
        unsigned long long mask = ~0ull;
        #pragma unroll
        for (int bit = 0; bit < 6; ++bit) {
            unsigned long long bb = __ballot((ld >> bit) & 1);
            mask &= ((ld >> bit) & 1) ? bb : ~bb;
        }
        mask &= __ballot(1);
        int rank = __popcll(mask & ((1ull << lane) - 1ull));
        float* row = &wreg[ld * 9];
        for (int r = 0; r < 64; ++r) {
            if (__ballot(rank == r) == 0ull) break;
            if (rank == r) {
                row[0] += w;
                row[1] = fmaf(w, ha.x, row[1]); row[2] = fmaf(w, ha.y, row[2]);
                row[3] = fmaf(w, ha.z, row[3]); row[4] = fmaf(w, ha.w, row[4]);
                row[5] = fmaf(w, hb.x, row[5]); row[6] = fmaf(w, hb.y, row[6]);
                row[7] = fmaf(w, hb.z, row[7]); row[8] = fmaf(w, hb.w, row[8]);
            }
        }
        p = pn; i = inx;
    }
    __syncthreads();
    if (t < nw) {
        int n = node0 + t;
        float v = als2[n] + adl[t];               // self-loop
        v = (v > 0.f) ? v : NEG_SLOPE * v;
        float ww = __expf(v);
        const float4* hv = (const float4*)&h2[(size_t)n * 8];
        float4 ha0 = hv[0], hb0 = hv[1];
        float acc[9];
        #pragma unroll
        for (int c = 0; c < 9; ++c) {
            float s = 0.f;
            #pragma unroll
            for (int r = 0; r < 8; ++r) s += R[r * 576 + t * 9 + c];
            acc[c] = s;
        }
        float s2 = acc[0] + ww;
        float inv = 1.f / s2;
        float4* ov = (float4*)&out[(size_t)n * 8];
        ov[0] = make_float4((acc[1] + ww * ha0.x) * inv + b2[0],
                            (acc[2] + ww * ha0.y) * inv + b2[1],
                            (acc[3] + ww * ha0.z) * inv + b2[2],
                            (acc[4] + ww * ha0.w) * inv + b2[3]);
        ov[1] = make_float4((acc[5] + ww * hb0.x) * inv + b2[4],
                            (acc[6] + ww * hb0.y) * inv + b2[5],
                            (acc[7] + ww * hb0.z) * inv + b2[6],
                            (acc[8] + ww * hb0.w) * inv + b2[7]);
    }
}

// ---------------- fallback path (R2, atomic-based; known-correct) ----------------

__global__ void prep_consts(const float* __restrict__ W1,
                            const float* __restrict__ as1,
                            const float* __restrict__ ad1,
                            float* __restrict__ consts) {
    int t = threadIdx.x;
    if (t >= 8) return;
    int h = t & 3;
    const float* a = (t < 4) ? as1 : ad1;
    float s = 0.f;
    #pragma unroll
    for (int c = 0; c < 8; ++c)
        s += W1[h * 8 + c] * a[h * 8 + c];
    consts[t] = s;
}

__global__ void edge_pass1(const int* __restrict__ ei, const float* __restrict__ x,
                           const float* __restrict__ consts,
                           float* __restrict__ s1, float* __restrict__ t1, int E, int N) {
    int e = blockIdx.x * blockDim.x + threadIdx.x;
    if (e >= E + N) return;
    int src, dst;
    if (e < E) { src = ei[e]; dst = ei[E + e]; }
    else       { src = dst = e - E; }
    float xs = x[src], xd = x[dst];
    #pragma unroll
    for (int h = 0; h < 4; ++h) {
        float v = xs * consts[h] + xd * consts[4 + h];
        v = (v > 0.f) ? v : NEG_SLOPE * v;
        float w = __expf(v);
        atomicAdd(&s1[dst * 4 + h], w);
        atomicAdd(&t1[dst * 4 + h], w * xs);
    }
}

__global__ void node_mid(const float* __restrict__ s1, const float* __restrict__ t1,
                         const float* __restrict__ W1, const float* __restrict__ b1,
                         const float* __restrict__ W2,
                         const float* __restrict__ as2, const float* __restrict__ ad2,
                         float* __restrict__ h2, float* __restrict__ als2,
                         float* __restrict__ ald2, int N) {
    int n = blockIdx.x * blockDim.x + threadIdx.x;
    if (n >= N) return;
    float o[8];
    #pragma unroll
    for (int c = 0; c < 8; ++c) o[c] = 0.f;
    #pragma unroll
    for (int h = 0; h < 4; ++h) {
        float t = t1[n * 4 + h] / s1[n * 4 + h];
        #pragma unroll
        for (int c = 0; c < 8; ++c) {
            float r = fmaxf(t * W1[h * 8 + c] + b1[h * 8 + c], 0.f);
            #pragma unroll
            for (int c2 = 0; c2 < 8; ++c2) o[c2] += r * W2[(h * 8 + c) * 8 + c2];
        }
    }
    float as = 0.f, ad = 0.f;
    #pragma unroll
    for (int c = 0; c < 8; ++c) { h2[n * 8 + c] = o[c]; as += o[c] * as2[c]; ad += o[c] * ad2[c]; }
    als2[n] = as; ald2[n] = ad;
}

__global__ void edge_pass2(const int* __restrict__ ei, const float* __restrict__ als2,
                           const float* __restrict__ ald2, const float* __restrict__ h2,
                           float* __restrict__ s2, float* __restrict__ acc2, int E, int N) {
    int e = blockIdx.x * blockDim.x + threadIdx.x;
    if (e >= E + N) return;
    int src, dst;
    if (e < E) { src = ei[e]; dst = ei[E + e]; }
    else       { src = dst = e - E; }
    float v = als2[src] + ald2[dst];
    v = (v > 0.f) ? v : NEG_SLOPE * v;
    float w = __expf(v);
    atomicAdd(&s2[dst], w);
    const float4* hs = (const float4*)&h2[src * 8];
    float4 a = hs[0], bq = hs[1];
    float* acc = &acc2[dst * 8];
    atomicAdd(&acc[0], w * a.x);  atomicAdd(&acc[1], w * a.y);
    atomicAdd(&acc[2], w * a.z);  atomicAdd(&acc[3], w * a.w);
    atomicAdd(&acc[4], w * bq.x); atomicAdd(&acc[5], w * bq.y);
    atomicAdd(&acc[6], w * bq.z); atomicAdd(&acc[7], w * bq.w);
}

__global__ void node_out(const float* __restrict__ s2, const float* __restrict__ acc2,
                         const float* __restrict__ b2, float* __restrict__ out, int N) {
    int i = blockIdx.x * blockDim.x + threadIdx.x;
    if (i >= N * 8) return;
    out[i] = acc2[i] / s2[i >> 3] + b2[i & 7];
}

// ---------------------------------------------------------------------------

extern "C" void kernel_launch(void* const* d_in, const int* in_sizes, int n_in,
                              void* d_out, int out_size, void* d_ws, size_t ws_size,
                              hipStream_t stream) {
    const float* x   = (const float*)d_in[0];
    const int*   ei  = (const int*)d_in[1];
    const float* W1  = (const float*)d_in[2];
    const float* as1 = (const float*)d_in[3];
    const float* ad1 = (const float*)d_in[4];
    const float* b1  = (const float*)d_in[5];
    const float* W2  = (const float*)d_in[6];
    const float* as2 = (const float*)d_in[7];
    const float* ad2 = (const float*)d_in[8];
    const float* b2  = (const float*)d_in[9];
    float* out = (float*)d_out;

    const int N = in_sizes[0];          // 100000
    const int E = in_sizes[1] / 2;      // 3200000
    const int NBK = (N + 63) >> 6;      // 1563 buckets of 64 nodes

    float* ws = (float*)d_ws;
    size_t need = (size_t)(16 + 3 * 2048 + 10 * (size_t)N + (size_t)E) * sizeof(float);

    if (N <= 131072 && ws_size >= need) {
        float*    consts  = ws;                          // 16
        int*      gcnt    = (int*)(ws + 16);             // 2048
        int*      gbase   = gcnt + 2048;                 // 2048
        int*      gcursor = gbase + 2048;                // 2048
        float*    als2    = ws + 16 + 3 * 2048;          // N
        float*    ald2    = als2 + N;                    // N
        float*    h2      = ald2 + N;                    // 8N
        unsigned* pairs   = (unsigned*)(h2 + 8 * (size_t)N);  // E

        hipMemsetAsync(gcnt, 0, 2048 * sizeof(int), stream);
        bucket_hist<<<256, 256, 0, stream>>>(ei, gcnt, E);
        scan_init<<<1, 512, 0, stream>>>(gcnt, gbase, gcursor, W1, as1, ad1, consts);
        bucket_scatter<<<256, 1024, 0, stream>>>(ei, gcursor, pairs, E);
        l1_comb<<<NBK, 512, 0, stream>>>(x, gbase, gcnt, pairs, consts,
                                         W1, b1, W2, as2, ad2, h2, als2, ald2, N);
        l2_comb<<<NBK, 512, 0, stream>>>(gbase, gcnt, pairs, als2, ald2, h2, b2, out, N);
    } else {
        // fallback: R2 atomic path (10.8 MB ws, known-correct)
        float* consts = ws;
        float* s1   = ws + 16;
        float* t1   = s1 + 4 * (size_t)N;
        float* h2   = t1 + 4 * (size_t)N;
        float* als2 = h2 + 8 * (size_t)N;
        float* ald2 = als2 + (size_t)N;
        float* s2   = ald2 + (size_t)N;
        float* acc2 = s2 + (size_t)N;

        hipMemsetAsync(ws, 0, (16 + 8 * (size_t)N) * sizeof(float), stream);
        hipMemsetAsync(s2, 0, 9 * (size_t)N * sizeof(float), stream);
        prep_consts<<<1, 64, 0, stream>>>(W1, as1, ad1, consts);
        int total = E + N;
        edge_pass1<<<(total + 255) / 256, 256, 0, stream>>>(ei, x, consts, s1, t1, E, N);
        node_mid<<<(N + 255) / 256, 256, 0, stream>>>(s1, t1, W1, b1, W2, as2, ad2, h2, als2, ald2, N);
        edge_pass2<<<(total + 255) / 256, 256, 0, stream>>>(ei, als2, ald2, h2, s2, acc2, E, N);
        node_out<<<(N * 8 + 255) / 256, 256, 0, stream>>>(s2, acc2, b2, out, N);
    }
}